// Round 1
// baseline (1163.049 us; speedup 1.0000x reference)
//
#include <hip/hip_runtime.h>
#include <stdint.h>

#define Nn 256
#define Mm 512
#define Dd 256

typedef unsigned short u16;
typedef __attribute__((ext_vector_type(8))) short bf16x8;
typedef __attribute__((ext_vector_type(4))) float f32x4;
typedef __attribute__((ext_vector_type(4))) int i32x4;

__device__ __forceinline__ u16 f2b(float f) {
    unsigned u = __float_as_uint(f);
    return (u16)((u + 0x7FFFu + ((u >> 16) & 1u)) >> 16);  // RNE to bf16
}
__device__ __forceinline__ float b2f(u16 h) {
    return __uint_as_float(((unsigned)h) << 16);
}

// ---------------------------------------------------------------------------
// Kernel 1: per-(n,d) mean over m, center, emit xn (bf16, [n][m][d]) and
// xnT (bf16, [n][d][m]) via LDS transpose. One block per batch n.
// ---------------------------------------------------------------------------
__global__ __launch_bounds__(256) void center_kernel(const float* __restrict__ x,
                                                     u16* __restrict__ xn,
                                                     u16* __restrict__ xnT) {
    __shared__ float meanS[Dd];
    __shared__ u16 tileS[64 * 66];  // [d_local][m_local], stride 66 -> 2-way banks (free)
    const int n = blockIdx.x;
    const int tid = threadIdx.x;
    const float* xb = x + (size_t)n * Mm * Dd;

    float s = 0.f;
    for (int m = 0; m < Mm; ++m) s += xb[m * Dd + tid];   // coalesced over d
    meanS[tid] = s * (1.0f / Mm);
    __syncthreads();

    const int tx = tid & 63, ty = tid >> 6;  // ty in 0..3
    u16* xnb = xn + (size_t)n * Mm * Dd;
    u16* xtb = xnT + (size_t)n * Dd * Mm;

    for (int mt = 0; mt < Mm / 64; ++mt) {
        for (int dt = 0; dt < Dd / 64; ++dt) {
            #pragma unroll 4
            for (int r = 0; r < 16; ++r) {
                int ml = r * 4 + ty;
                int m = mt * 64 + ml;
                int d = dt * 64 + tx;
                float v = xb[m * Dd + d] - meanS[d];
                u16 b = f2b(v);
                xnb[m * Dd + d] = b;
                tileS[tx * 66 + ml] = b;
            }
            __syncthreads();
            #pragma unroll 4
            for (int r = 0; r < 16; ++r) {
                int dl = r * 4 + ty;
                xtb[(size_t)(dt * 64 + dl) * Mm + mt * 64 + tx] = tileS[dl * 66 + tx];
            }
            __syncthreads();
        }
    }
}

// ---------------------------------------------------------------------------
// Kernel 2: sigma[n] = XnT @ XnT^T  (raw, no /(M-1)).  C[d1][d2] = sum_m.
// Both MFMA operands read K(=m)-contiguous rows of xnT. 128x128 tile, BK=32.
// ---------------------------------------------------------------------------
__global__ __launch_bounds__(256) void sigma_kernel(const u16* __restrict__ xnT,
                                                    float* __restrict__ sigma) {
    __shared__ u16 sA[128 * 40];
    __shared__ u16 sB[128 * 40];
    const int bid = blockIdx.x;
    const int n = bid >> 2;
    const int tr = (bid >> 1) & 1, tc = bid & 1;
    const int tid = threadIdx.x;
    const int lane = tid & 63, wave = tid >> 6;
    const int wr = wave >> 1, wc = wave & 1;
    const int l15 = lane & 15, quad = lane >> 4;

    const u16* base = xnT + (size_t)n * Dd * Mm;
    const u16* gA = base + (size_t)(tr * 128) * Mm;
    const u16* gB = base + (size_t)(tc * 128) * Mm;

    const int s0 = tid, s1 = tid + 256;
    const int r0 = s0 >> 2, q0 = s0 & 3;
    const int r1 = s1 >> 2, q1 = s1 & 3;

    f32x4 acc[4][4];
    #pragma unroll
    for (int i = 0; i < 4; ++i)
        #pragma unroll
        for (int j = 0; j < 4; ++j) acc[i][j] = (f32x4){0.f, 0.f, 0.f, 0.f};

    for (int kk = 0; kk < Mm; kk += 32) {
        __syncthreads();
        *(i32x4*)(sA + r0 * 40 + q0 * 8) = *(const i32x4*)(gA + (size_t)r0 * Mm + kk + q0 * 8);
        *(i32x4*)(sA + r1 * 40 + q1 * 8) = *(const i32x4*)(gA + (size_t)r1 * Mm + kk + q1 * 8);
        *(i32x4*)(sB + r0 * 40 + q0 * 8) = *(const i32x4*)(gB + (size_t)r0 * Mm + kk + q0 * 8);
        *(i32x4*)(sB + r1 * 40 + q1 * 8) = *(const i32x4*)(gB + (size_t)r1 * Mm + kk + q1 * 8);
        __syncthreads();
        bf16x8 a[4], b[4];
        #pragma unroll
        for (int i = 0; i < 4; ++i) a[i] = *(const bf16x8*)(sA + (wr * 64 + i * 16 + l15) * 40 + quad * 8);
        #pragma unroll
        for (int j = 0; j < 4; ++j) b[j] = *(const bf16x8*)(sB + (wc * 64 + j * 16 + l15) * 40 + quad * 8);
        #pragma unroll
        for (int i = 0; i < 4; ++i)
            #pragma unroll
            for (int j = 0; j < 4; ++j)
                acc[i][j] = __builtin_amdgcn_mfma_f32_16x16x32_bf16(a[i], b[j], acc[i][j], 0, 0, 0);
    }

    float* sg = sigma + (size_t)n * Dd * Dd;
    #pragma unroll
    for (int i = 0; i < 4; ++i)
        #pragma unroll
        for (int j = 0; j < 4; ++j)
            #pragma unroll
            for (int r = 0; r < 4; ++r) {
                int row = tr * 128 + wr * 64 + i * 16 + quad * 4 + r;
                int col = tc * 128 + wc * 64 + j * 16 + l15;
                sg[row * Dd + col] = acc[i][j][r];
            }
}

// ---------------------------------------------------------------------------
// Kernel 3: trace reduce, S = sigma/raw_tr (split hi/lo), P1 = 1.5I - 0.5S
// (split), rtr[n] = 1/sqrt(raw_tr/511). One block per batch.
// ---------------------------------------------------------------------------
__global__ __launch_bounds__(256) void normalize_kernel(const float* __restrict__ sigma,
                                                        u16* __restrict__ Sh, u16* __restrict__ Sl,
                                                        u16* __restrict__ Ph, u16* __restrict__ Pl,
                                                        float* __restrict__ rtr) {
    __shared__ float red[256];
    const int n = blockIdx.x, tid = threadIdx.x;
    const float* sg = sigma + (size_t)n * Dd * Dd;
    red[tid] = sg[tid * (Dd + 1)];
    __syncthreads();
    for (int s = 128; s > 0; s >>= 1) {
        if (tid < s) red[tid] += red[tid + s];
        __syncthreads();
    }
    const float raw = red[0];
    const float inv = 1.0f / raw;
    if (tid == 0) rtr[n] = sqrtf(511.0f * inv);

    const size_t mb = (size_t)n * Dd * Dd;
    for (int r = 0; r < Dd; ++r) {
        size_t idx = mb + (size_t)r * Dd + tid;
        float s = sg[r * Dd + tid] * inv;
        u16 sh = f2b(s);
        Sh[idx] = sh;
        Sl[idx] = f2b(s - b2f(sh));
        float p = ((r == tid) ? 1.5f : 0.0f) - 0.5f * s;
        u16 ph = f2b(p);
        Ph[idx] = ph;
        Pl[idx] = f2b(p - b2f(ph));
    }
}

// ---------------------------------------------------------------------------
// Kernel 4: split-bf16 batched GEMM C = A@B (A,B symmetric 256x256, given as
// hi/lo bf16 pairs). acc = Ah*Bh + Ah*Bl + Al*Bh (fp32 MFMA accum).
//  mode 0: write split(acc) -> outH/outL
//  mode 1: Pnew = 1.5*(Ph+Pl) - 0.5*acc, write split in-place to Ph/Pl
//  mode 2: W = (1.5*(Ph+Pl) - 0.5*acc) * rtr[n], write bf16 -> outH
// B-fragments read ROWS of B (valid because B is symmetric).
// ---------------------------------------------------------------------------
__global__ __launch_bounds__(256) void ns_gemm(const u16* __restrict__ Ah, const u16* __restrict__ Al,
                                               const u16* __restrict__ Bh, const u16* __restrict__ Bl,
                                               u16* __restrict__ outH, u16* __restrict__ outL,
                                               u16* __restrict__ Pbh, u16* __restrict__ Pbl,
                                               const float* __restrict__ rtr, int mode) {
    __shared__ u16 sAh[128 * 40], sAl[128 * 40], sBh[128 * 40], sBl[128 * 40];
    const int bid = blockIdx.x;
    const int n = bid >> 2;
    const int tr = (bid >> 1) & 1, tc = bid & 1;
    const int tid = threadIdx.x;
    const int lane = tid & 63, wave = tid >> 6;
    const int wr = wave >> 1, wc = wave & 1;
    const int l15 = lane & 15, quad = lane >> 4;

    const size_t mb = (size_t)n * Dd * Dd;
    const u16* gAh = Ah + mb + (size_t)(tr * 128) * Dd;
    const u16* gAl = Al + mb + (size_t)(tr * 128) * Dd;
    const u16* gBh = Bh + mb + (size_t)(tc * 128) * Dd;
    const u16* gBl = Bl + mb + (size_t)(tc * 128) * Dd;

    const int s0 = tid, s1 = tid + 256;
    const int r0 = s0 >> 2, q0 = s0 & 3;
    const int r1 = s1 >> 2, q1 = s1 & 3;

    f32x4 acc[4][4];
    #pragma unroll
    for (int i = 0; i < 4; ++i)
        #pragma unroll
        for (int j = 0; j < 4; ++j) acc[i][j] = (f32x4){0.f, 0.f, 0.f, 0.f};

    for (int kk = 0; kk < Dd; kk += 32) {
        __syncthreads();
        *(i32x4*)(sAh + r0 * 40 + q0 * 8) = *(const i32x4*)(gAh + (size_t)r0 * Dd + kk + q0 * 8);
        *(i32x4*)(sAh + r1 * 40 + q1 * 8) = *(const i32x4*)(gAh + (size_t)r1 * Dd + kk + q1 * 8);
        *(i32x4*)(sAl + r0 * 40 + q0 * 8) = *(const i32x4*)(gAl + (size_t)r0 * Dd + kk + q0 * 8);
        *(i32x4*)(sAl + r1 * 40 + q1 * 8) = *(const i32x4*)(gAl + (size_t)r1 * Dd + kk + q1 * 8);
        *(i32x4*)(sBh + r0 * 40 + q0 * 8) = *(const i32x4*)(gBh + (size_t)r0 * Dd + kk + q0 * 8);
        *(i32x4*)(sBh + r1 * 40 + q1 * 8) = *(const i32x4*)(gBh + (size_t)r1 * Dd + kk + q1 * 8);
        *(i32x4*)(sBl + r0 * 40 + q0 * 8) = *(const i32x4*)(gBl + (size_t)r0 * Dd + kk + q0 * 8);
        *(i32x4*)(sBl + r1 * 40 + q1 * 8) = *(const i32x4*)(gBl + (size_t)r1 * Dd + kk + q1 * 8);
        __syncthreads();
        bf16x8 ah[4], al[4], bh[4], bl[4];
        #pragma unroll
        for (int i = 0; i < 4; ++i) {
            int off = (wr * 64 + i * 16 + l15) * 40 + quad * 8;
            ah[i] = *(const bf16x8*)(sAh + off);
            al[i] = *(const bf16x8*)(sAl + off);
        }
        #pragma unroll
        for (int j = 0; j < 4; ++j) {
            int off = (wc * 64 + j * 16 + l15) * 40 + quad * 8;
            bh[j] = *(const bf16x8*)(sBh + off);
            bl[j] = *(const bf16x8*)(sBl + off);
        }
        #pragma unroll
        for (int i = 0; i < 4; ++i)
            #pragma unroll
            for (int j = 0; j < 4; ++j) {
                acc[i][j] = __builtin_amdgcn_mfma_f32_16x16x32_bf16(ah[i], bh[j], acc[i][j], 0, 0, 0);
                acc[i][j] = __builtin_amdgcn_mfma_f32_16x16x32_bf16(ah[i], bl[j], acc[i][j], 0, 0, 0);
                acc[i][j] = __builtin_amdgcn_mfma_f32_16x16x32_bf16(al[i], bh[j], acc[i][j], 0, 0, 0);
            }
    }

    const float rs = rtr[n];
    #pragma unroll
    for (int i = 0; i < 4; ++i)
        #pragma unroll
        for (int j = 0; j < 4; ++j)
            #pragma unroll
            for (int r = 0; r < 4; ++r) {
                int row = tr * 128 + wr * 64 + i * 16 + quad * 4 + r;
                int col = tc * 128 + wc * 64 + j * 16 + l15;
                size_t idx = mb + (size_t)row * Dd + col;
                float v = acc[i][j][r];
                if (mode == 0) {
                    u16 h = f2b(v);
                    outH[idx] = h;
                    outL[idx] = f2b(v - b2f(h));
                } else {
                    float p = b2f(Pbh[idx]) + b2f(Pbl[idx]);
                    float pn = 1.5f * p - 0.5f * v;
                    if (mode == 1) {
                        u16 h = f2b(pn);
                        Pbh[idx] = h;
                        Pbl[idx] = f2b(pn - b2f(h));
                    } else {
                        outH[idx] = f2b(pn * rs);
                    }
                }
            }
}

// ---------------------------------------------------------------------------
// Kernel 5: out = Xn @ W  (plain bf16; W symmetric -> B reads rows). fp32 out.
// ---------------------------------------------------------------------------
__global__ __launch_bounds__(256) void final_gemm(const u16* __restrict__ xn,
                                                  const u16* __restrict__ Wh,
                                                  float* __restrict__ out) {
    __shared__ u16 sA[128 * 40];
    __shared__ u16 sB[128 * 40];
    const int bid = blockIdx.x;
    const int n = bid >> 3;
    const int t = bid & 7;
    const int tr = t >> 1;  // m-tile 0..3
    const int tc = t & 1;   // d-tile 0..1
    const int tid = threadIdx.x;
    const int lane = tid & 63, wave = tid >> 6;
    const int wr = wave >> 1, wc = wave & 1;
    const int l15 = lane & 15, quad = lane >> 4;

    const u16* gA = xn + (size_t)n * Mm * Dd + (size_t)(tr * 128) * Dd;
    const u16* gB = Wh + (size_t)n * Dd * Dd + (size_t)(tc * 128) * Dd;

    const int s0 = tid, s1 = tid + 256;
    const int r0 = s0 >> 2, q0 = s0 & 3;
    const int r1 = s1 >> 2, q1 = s1 & 3;

    f32x4 acc[4][4];
    #pragma unroll
    for (int i = 0; i < 4; ++i)
        #pragma unroll
        for (int j = 0; j < 4; ++j) acc[i][j] = (f32x4){0.f, 0.f, 0.f, 0.f};

    for (int kk = 0; kk < Dd; kk += 32) {
        __syncthreads();
        *(i32x4*)(sA + r0 * 40 + q0 * 8) = *(const i32x4*)(gA + (size_t)r0 * Dd + kk + q0 * 8);
        *(i32x4*)(sA + r1 * 40 + q1 * 8) = *(const i32x4*)(gA + (size_t)r1 * Dd + kk + q1 * 8);
        *(i32x4*)(sB + r0 * 40 + q0 * 8) = *(const i32x4*)(gB + (size_t)r0 * Dd + kk + q0 * 8);
        *(i32x4*)(sB + r1 * 40 + q1 * 8) = *(const i32x4*)(gB + (size_t)r1 * Dd + kk + q1 * 8);
        __syncthreads();
        bf16x8 a[4], b[4];
        #pragma unroll
        for (int i = 0; i < 4; ++i) a[i] = *(const bf16x8*)(sA + (wr * 64 + i * 16 + l15) * 40 + quad * 8);
        #pragma unroll
        for (int j = 0; j < 4; ++j) b[j] = *(const bf16x8*)(sB + (wc * 64 + j * 16 + l15) * 40 + quad * 8);
        #pragma unroll
        for (int i = 0; i < 4; ++i)
            #pragma unroll
            for (int j = 0; j < 4; ++j)
                acc[i][j] = __builtin_amdgcn_mfma_f32_16x16x32_bf16(a[i], b[j], acc[i][j], 0, 0, 0);
    }

    float* ob = out + (size_t)n * Mm * Dd;
    #pragma unroll
    for (int i = 0; i < 4; ++i)
        #pragma unroll
        for (int j = 0; j < 4; ++j)
            #pragma unroll
            for (int r = 0; r < 4; ++r) {
                int row = tr * 128 + wr * 64 + i * 16 + quad * 4 + r;
                int col = tc * 128 + wc * 64 + j * 16 + l15;
                ob[(size_t)row * Dd + col] = acc[i][j][r];
            }
}

// ---------------------------------------------------------------------------
// Workspace layout (bytes):
//   xn   :        0 .. 64MB   bf16 [N][M][D]
//   xnT  :     64MB .. 128MB  bf16 [N][D][M]   (reused as Qh/Ql, then Wh)
//   sigma:    128MB .. 192MB  f32  [N][D][D]   (reused as Rh/Rl)
//   Sh   :    192MB .. 224MB
//   Sl   :    224MB .. 256MB
//   Ph   :    256MB .. 288MB
//   Pl   :    288MB .. 320MB
//   rtr  :    320MB .. +1KB
// Total ~320MB.
// ---------------------------------------------------------------------------
extern "C" void kernel_launch(void* const* d_in, const int* in_sizes, int n_in,
                              void* d_out, int out_size, void* d_ws, size_t ws_size,
                              hipStream_t stream) {
    const float* x = (const float*)d_in[0];
    float* out = (float*)d_out;
    char* ws = (char*)d_ws;

    const size_t MB32 = 33554432;
    u16* xn = (u16*)(ws + 0);
    u16* xnT = (u16*)(ws + 2 * MB32);
    float* sigma = (float*)(ws + 4 * MB32);
    u16* Sh = (u16*)(ws + 6 * MB32);
    u16* Sl = (u16*)(ws + 7 * MB32);
    u16* Ph = (u16*)(ws + 8 * MB32);
    u16* Pl = (u16*)(ws + 9 * MB32);
    float* rtr = (float*)(ws + 10 * MB32);
    // aliases (lifetimes disjoint):
    u16* Qh = (u16*)(ws + 2 * MB32);  // over xnT (dead after sigma_kernel)
    u16* Ql = (u16*)(ws + 3 * MB32);
    u16* Rh = (u16*)(ws + 4 * MB32);  // over sigma (dead after normalize)
    u16* Rl = (u16*)(ws + 5 * MB32);
    u16* Wh = Qh;                     // Q dead when last K3 runs

    center_kernel<<<Nn, 256, 0, stream>>>(x, xn, xnT);
    sigma_kernel<<<Nn * 4, 256, 0, stream>>>(xnT, sigma);
    normalize_kernel<<<Nn, 256, 0, stream>>>(sigma, Sh, Sl, Ph, Pl, rtr);

    // Newton-Schulz iterations 2..4 (iteration 1 fused into normalize_kernel)
    for (int it = 1; it < 4; ++it) {
        // Q = P @ P
        ns_gemm<<<Nn * 4, 256, 0, stream>>>(Ph, Pl, Ph, Pl, Qh, Ql, Ph, Pl, rtr, 0);
        // R = Q @ P
        ns_gemm<<<Nn * 4, 256, 0, stream>>>(Qh, Ql, Ph, Pl, Rh, Rl, Ph, Pl, rtr, 0);
        // T = R @ S ; P = 1.5P - 0.5T   (last iter: W = P_new * rtr)
        int mode = (it == 3) ? 2 : 1;
        ns_gemm<<<Nn * 4, 256, 0, stream>>>(Rh, Rl, Sh, Sl, Wh, Ql, Ph, Pl, rtr, mode);
    }

    final_gemm<<<Nn * 8, 256, 0, stream>>>(xn, Wh, out);
}

// Round 2
// 822.575 us; speedup vs baseline: 1.4139x; 1.4139x over previous
//
#include <hip/hip_runtime.h>
#include <stdint.h>

#define Nn 256
#define Mm 512
#define Dd 256

typedef unsigned short u16;
typedef unsigned int u32;
typedef __attribute__((ext_vector_type(8))) short bf16x8;
typedef __attribute__((ext_vector_type(4))) float f32x4;

__device__ __forceinline__ u16 f2b(float f) {
    unsigned u = __float_as_uint(f);
    return (u16)((u + 0x7FFFu + ((u >> 16) & 1u)) >> 16);  // RNE to bf16
}
__device__ __forceinline__ float b2f(u16 h) {
    return __uint_as_float(((unsigned)h) << 16);
}
__device__ __forceinline__ void glds16(const u16* g, u16* l) {
    __builtin_amdgcn_global_load_lds((const __attribute__((address_space(1))) void*)g,
                                     (__attribute__((address_space(3))) void*)l, 16, 0, 0);
}

// ---------------------------------------------------------------------------
// Kernel 1: per-(n,d) mean over m, center, emit xn bf16 [n][m][d] and
// xnT bf16 [n][d][m] via LDS transpose. One block per batch n.
// ---------------------------------------------------------------------------
__global__ __launch_bounds__(256) void center_kernel(const float* __restrict__ x,
                                                     u16* __restrict__ xn,
                                                     u16* __restrict__ xnT) {
    __shared__ float meanS[Dd];
    __shared__ u16 tileS[64 * 66];
    const int n = blockIdx.x, tid = threadIdx.x;
    const float* xb = x + (size_t)n * Mm * Dd;

    float a0 = 0.f, a1 = 0.f, a2 = 0.f, a3 = 0.f;
    for (int m = 0; m < Mm; m += 4) {
        a0 += xb[(m + 0) * Dd + tid];
        a1 += xb[(m + 1) * Dd + tid];
        a2 += xb[(m + 2) * Dd + tid];
        a3 += xb[(m + 3) * Dd + tid];
    }
    meanS[tid] = (a0 + a1 + a2 + a3) * (1.0f / Mm);
    __syncthreads();

    u16* xnb = xn + (size_t)n * Mm * Dd;
    u16* xtb = xnT + (size_t)n * Dd * Mm;
    const int mrow = tid >> 4, dq = tid & 15;     // phase A mapping
    const int tx2 = (tid & 31) * 2, ty = tid >> 5; // phase B mapping

    for (int mt = 0; mt < Mm / 64; ++mt) {
        for (int dt = 0; dt < Dd / 64; ++dt) {
            #pragma unroll
            for (int rr = 0; rr < 4; ++rr) {
                int ml = mrow + 16 * rr;
                int m = mt * 64 + ml;
                int d = dt * 64 + dq * 4;
                float4 v = *(const float4*)(xb + (size_t)m * Dd + d);
                float4 mu = *(const float4*)(meanS + d);
                u16 b0 = f2b(v.x - mu.x), b1 = f2b(v.y - mu.y);
                u16 b2 = f2b(v.z - mu.z), b3 = f2b(v.w - mu.w);
                u32 lo = (u32)b0 | ((u32)b1 << 16);
                u32 hi = (u32)b2 | ((u32)b3 << 16);
                *(uint2*)(xnb + (size_t)m * Dd + d) = make_uint2(lo, hi);
                tileS[(dq * 4 + 0) * 66 + ml] = b0;
                tileS[(dq * 4 + 1) * 66 + ml] = b1;
                tileS[(dq * 4 + 2) * 66 + ml] = b2;
                tileS[(dq * 4 + 3) * 66 + ml] = b3;
            }
            __syncthreads();
            #pragma unroll
            for (int r = 0; r < 8; ++r) {
                int dl = r * 8 + ty;
                u32 w = *(const u32*)(tileS + dl * 66 + tx2);
                *(u32*)(xtb + (size_t)(dt * 64 + dl) * Mm + mt * 64 + tx2) = w;
            }
            __syncthreads();
        }
    }
}

// ---------------------------------------------------------------------------
// Kernel 2: sigma[n] = XnT @ XnT^T (raw). XCD-swizzled: batch's 4 blocks on
// one XCD. LDS [128][32] unpadded, global_load_lds staging.
// ---------------------------------------------------------------------------
__global__ __launch_bounds__(256) void sigma_kernel(const u16* __restrict__ xnT,
                                                    float* __restrict__ sigma) {
    __shared__ u16 sA[128 * 32];
    __shared__ u16 sB[128 * 32];
    const int bid = blockIdx.x;
    const int xcd = bid & 7, slot = bid >> 3;
    const int t = slot & 3;
    const int n = ((slot >> 2) << 3) | xcd;
    const int tr = t >> 1, tc = t & 1;
    const int tid = threadIdx.x;
    const int lane = tid & 63, wave = tid >> 6;
    const int wr = wave >> 1, wc = wave & 1;
    const int l15 = lane & 15, quad = lane >> 4;
    const int row0 = tid >> 2, q = tid & 3;
    const int wb8 = (tid & 192) * 8;  // wave-uniform LDS u16 offset

    const u16* base = xnT + (size_t)n * Dd * Mm;
    const u16* gA = base + (size_t)(tr * 128) * Mm;
    const u16* gB = base + (size_t)(tc * 128) * Mm;

    f32x4 acc[4][4];
    #pragma unroll
    for (int i = 0; i < 4; ++i)
        #pragma unroll
        for (int j = 0; j < 4; ++j) acc[i][j] = (f32x4){0.f, 0.f, 0.f, 0.f};

    for (int kk = 0; kk < Mm; kk += 32) {
        glds16(gA + (size_t)row0 * Mm + kk + q * 8, sA + wb8);
        glds16(gA + (size_t)(row0 + 64) * Mm + kk + q * 8, sA + 2048 + wb8);
        glds16(gB + (size_t)row0 * Mm + kk + q * 8, sB + wb8);
        glds16(gB + (size_t)(row0 + 64) * Mm + kk + q * 8, sB + 2048 + wb8);
        __syncthreads();
        bf16x8 a[4], b[4];
        #pragma unroll
        for (int i = 0; i < 4; ++i) a[i] = *(const bf16x8*)(sA + (wr * 64 + i * 16 + l15) * 32 + quad * 8);
        #pragma unroll
        for (int j = 0; j < 4; ++j) b[j] = *(const bf16x8*)(sB + (wc * 64 + j * 16 + l15) * 32 + quad * 8);
        #pragma unroll
        for (int i = 0; i < 4; ++i)
            #pragma unroll
            for (int j = 0; j < 4; ++j)
                acc[i][j] = __builtin_amdgcn_mfma_f32_16x16x32_bf16(a[i], b[j], acc[i][j], 0, 0, 0);
        __syncthreads();
    }

    float* sg = sigma + (size_t)n * Dd * Dd;
    #pragma unroll
    for (int i = 0; i < 4; ++i)
        #pragma unroll
        for (int j = 0; j < 4; ++j)
            #pragma unroll
            for (int r = 0; r < 4; ++r) {
                int row = tr * 128 + wr * 64 + i * 16 + quad * 4 + r;
                int col = tc * 128 + wc * 64 + j * 16 + l15;
                sg[row * Dd + col] = acc[i][j][r];
            }
}

// ---------------------------------------------------------------------------
// Kernel 3: trace reduce, S = sigma/raw_tr (split hi/lo), P1 = 1.5I - 0.5S
// (split), rtr[n] = sqrt(511/raw_tr). One block per batch.
// ---------------------------------------------------------------------------
__global__ __launch_bounds__(256) void normalize_kernel(const float* __restrict__ sigma,
                                                        u16* __restrict__ Sh, u16* __restrict__ Sl,
                                                        u16* __restrict__ Ph, u16* __restrict__ Pl,
                                                        float* __restrict__ rtr) {
    __shared__ float red[256];
    const int n = blockIdx.x, tid = threadIdx.x;
    const float* sg = sigma + (size_t)n * Dd * Dd;
    red[tid] = sg[tid * (Dd + 1)];
    __syncthreads();
    for (int s = 128; s > 0; s >>= 1) {
        if (tid < s) red[tid] += red[tid + s];
        __syncthreads();
    }
    const float raw = red[0];
    const float inv = 1.0f / raw;
    if (tid == 0) rtr[n] = sqrtf(511.0f * inv);

    const size_t mb = (size_t)n * Dd * Dd;
    for (int r = 0; r < Dd; ++r) {
        size_t idx = mb + (size_t)r * Dd + tid;
        float s = sg[r * Dd + tid] * inv;
        u16 sh = f2b(s);
        Sh[idx] = sh;
        Sl[idx] = f2b(s - b2f(sh));
        float p = ((r == tid) ? 1.5f : 0.0f) - 0.5f * s;
        u16 ph = f2b(p);
        Ph[idx] = ph;
        Pl[idx] = f2b(p - b2f(ph));
    }
}

// ---------------------------------------------------------------------------
// Kernel 4: split-bf16 batched GEMM, C = A@B (A,B symmetric, hi/lo pairs).
// acc = Ah*Bh + Ah*Bl + Al*Bh.
//  mode 0: write split(acc) -> outH/outL            (Q = P@P, P' = P@E)
//  mode 1: E = 1.5I - 0.5*acc, write split -> outH/outL
//  mode 2: W = acc * rtr[n], write bf16 -> outH
// XCD-swizzled: batch's 4 blocks on one XCD.
// ---------------------------------------------------------------------------
__global__ __launch_bounds__(256) void ns_gemm(const u16* __restrict__ Ah, const u16* __restrict__ Al,
                                               const u16* __restrict__ Bh, const u16* __restrict__ Bl,
                                               u16* __restrict__ outH, u16* __restrict__ outL,
                                               const float* __restrict__ rtr, int mode) {
    __shared__ u16 sAh[128 * 32], sAl[128 * 32], sBh[128 * 32], sBl[128 * 32];
    const int bid = blockIdx.x;
    const int xcd = bid & 7, slot = bid >> 3;
    const int t = slot & 3;
    const int n = ((slot >> 2) << 3) | xcd;
    const int tr = t >> 1, tc = t & 1;
    const int tid = threadIdx.x;
    const int lane = tid & 63, wave = tid >> 6;
    const int wr = wave >> 1, wc = wave & 1;
    const int l15 = lane & 15, quad = lane >> 4;
    const int row0 = tid >> 2, q = tid & 3;
    const int wb8 = (tid & 192) * 8;

    const size_t mb = (size_t)n * Dd * Dd;
    const u16* gAh = Ah + mb + (size_t)(tr * 128) * Dd;
    const u16* gAl = Al + mb + (size_t)(tr * 128) * Dd;
    const u16* gBh = Bh + mb + (size_t)(tc * 128) * Dd;
    const u16* gBl = Bl + mb + (size_t)(tc * 128) * Dd;

    f32x4 acc[4][4];
    #pragma unroll
    for (int i = 0; i < 4; ++i)
        #pragma unroll
        for (int j = 0; j < 4; ++j) acc[i][j] = (f32x4){0.f, 0.f, 0.f, 0.f};

    for (int kk = 0; kk < Dd; kk += 32) {
        glds16(gAh + (size_t)row0 * Dd + kk + q * 8, sAh + wb8);
        glds16(gAh + (size_t)(row0 + 64) * Dd + kk + q * 8, sAh + 2048 + wb8);
        glds16(gAl + (size_t)row0 * Dd + kk + q * 8, sAl + wb8);
        glds16(gAl + (size_t)(row0 + 64) * Dd + kk + q * 8, sAl + 2048 + wb8);
        glds16(gBh + (size_t)row0 * Dd + kk + q * 8, sBh + wb8);
        glds16(gBh + (size_t)(row0 + 64) * Dd + kk + q * 8, sBh + 2048 + wb8);
        glds16(gBl + (size_t)row0 * Dd + kk + q * 8, sBl + wb8);
        glds16(gBl + (size_t)(row0 + 64) * Dd + kk + q * 8, sBl + 2048 + wb8);
        __syncthreads();
        bf16x8 ah[4], al[4], bh[4], bl[4];
        #pragma unroll
        for (int i = 0; i < 4; ++i) {
            int off = (wr * 64 + i * 16 + l15) * 32 + quad * 8;
            ah[i] = *(const bf16x8*)(sAh + off);
            al[i] = *(const bf16x8*)(sAl + off);
        }
        #pragma unroll
        for (int j = 0; j < 4; ++j) {
            int off = (wc * 64 + j * 16 + l15) * 32 + quad * 8;
            bh[j] = *(const bf16x8*)(sBh + off);
            bl[j] = *(const bf16x8*)(sBl + off);
        }
        #pragma unroll
        for (int i = 0; i < 4; ++i)
            #pragma unroll
            for (int j = 0; j < 4; ++j) {
                acc[i][j] = __builtin_amdgcn_mfma_f32_16x16x32_bf16(ah[i], bh[j], acc[i][j], 0, 0, 0);
                acc[i][j] = __builtin_amdgcn_mfma_f32_16x16x32_bf16(ah[i], bl[j], acc[i][j], 0, 0, 0);
                acc[i][j] = __builtin_amdgcn_mfma_f32_16x16x32_bf16(al[i], bh[j], acc[i][j], 0, 0, 0);
            }
        __syncthreads();
    }

    const float rs = (mode == 2) ? rtr[n] : 0.f;
    #pragma unroll
    for (int i = 0; i < 4; ++i)
        #pragma unroll
        for (int j = 0; j < 4; ++j)
            #pragma unroll
            for (int r = 0; r < 4; ++r) {
                int row = tr * 128 + wr * 64 + i * 16 + quad * 4 + r;
                int col = tc * 128 + wc * 64 + j * 16 + l15;
                size_t idx = mb + (size_t)row * Dd + col;
                float v = acc[i][j][r];
                if (mode == 0) {
                    u16 h = f2b(v);
                    outH[idx] = h;
                    outL[idx] = f2b(v - b2f(h));
                } else if (mode == 1) {
                    float e = ((row == col) ? 1.5f : 0.0f) - 0.5f * v;
                    u16 h = f2b(e);
                    outH[idx] = h;
                    outL[idx] = f2b(e - b2f(h));
                } else {
                    outH[idx] = f2b(v * rs);
                }
            }
}

// ---------------------------------------------------------------------------
// Kernel 5: out = Xn @ W (plain bf16; W symmetric -> B reads rows). fp32 out.
// XCD-swizzled: batch's 8 blocks on one XCD.
// ---------------------------------------------------------------------------
__global__ __launch_bounds__(256) void final_gemm(const u16* __restrict__ xn,
                                                  const u16* __restrict__ Wh,
                                                  float* __restrict__ out) {
    __shared__ u16 sA[128 * 32];
    __shared__ u16 sB[128 * 32];
    const int bid = blockIdx.x;
    const int xcd = bid & 7, slot = bid >> 3;
    const int t = slot & 7;
    const int n = ((slot >> 3) << 3) | xcd;
    const int tr = t >> 1;  // m-tile 0..3
    const int tc = t & 1;   // d-tile 0..1
    const int tid = threadIdx.x;
    const int lane = tid & 63, wave = tid >> 6;
    const int wr = wave >> 1, wc = wave & 1;
    const int l15 = lane & 15, quad = lane >> 4;
    const int row0 = tid >> 2, q = tid & 3;
    const int wb8 = (tid & 192) * 8;

    const u16* gA = xn + (size_t)n * Mm * Dd + (size_t)(tr * 128) * Dd;
    const u16* gB = Wh + (size_t)n * Dd * Dd + (size_t)(tc * 128) * Dd;

    f32x4 acc[4][4];
    #pragma unroll
    for (int i = 0; i < 4; ++i)
        #pragma unroll
        for (int j = 0; j < 4; ++j) acc[i][j] = (f32x4){0.f, 0.f, 0.f, 0.f};

    for (int kk = 0; kk < Dd; kk += 32) {
        glds16(gA + (size_t)row0 * Dd + kk + q * 8, sA + wb8);
        glds16(gA + (size_t)(row0 + 64) * Dd + kk + q * 8, sA + 2048 + wb8);
        glds16(gB + (size_t)row0 * Dd + kk + q * 8, sB + wb8);
        glds16(gB + (size_t)(row0 + 64) * Dd + kk + q * 8, sB + 2048 + wb8);
        __syncthreads();
        bf16x8 a[4], b[4];
        #pragma unroll
        for (int i = 0; i < 4; ++i) a[i] = *(const bf16x8*)(sA + (wr * 64 + i * 16 + l15) * 32 + quad * 8);
        #pragma unroll
        for (int j = 0; j < 4; ++j) b[j] = *(const bf16x8*)(sB + (wc * 64 + j * 16 + l15) * 32 + quad * 8);
        #pragma unroll
        for (int i = 0; i < 4; ++i)
            #pragma unroll
            for (int j = 0; j < 4; ++j)
                acc[i][j] = __builtin_amdgcn_mfma_f32_16x16x32_bf16(a[i], b[j], acc[i][j], 0, 0, 0);
        __syncthreads();
    }

    float* ob = out + (size_t)n * Mm * Dd;
    #pragma unroll
    for (int i = 0; i < 4; ++i)
        #pragma unroll
        for (int j = 0; j < 4; ++j)
            #pragma unroll
            for (int r = 0; r < 4; ++r) {
                int row = tr * 128 + wr * 64 + i * 16 + quad * 4 + r;
                int col = tc * 128 + wc * 64 + j * 16 + l15;
                ob[(size_t)row * Dd + col] = acc[i][j][r];
            }
}

// ---------------------------------------------------------------------------
// Workspace (32MB units): u0-1 xn | u2-3 xnT -> R1 (Q/P ping) | u4-5 sigma ->
// Eh/El | u6 Sh u7 Sl | u8-9 R2 (P pong) | u10 rtr. Total 320MB + 1KB.
// NS chain per iter: Q=P@P (mode0); E=1.5I-0.5(Q@S) (mode1); P'=P@E (mode0;
// last iter mode2 -> W bf16).
// ---------------------------------------------------------------------------
extern "C" void kernel_launch(void* const* d_in, const int* in_sizes, int n_in,
                              void* d_out, int out_size, void* d_ws, size_t ws_size,
                              hipStream_t stream) {
    const float* x = (const float*)d_in[0];
    float* out = (float*)d_out;
    char* ws = (char*)d_ws;
    const size_t MB32 = 33554432;

    u16* xn = (u16*)(ws + 0);
    u16* xnT = (u16*)(ws + 2 * MB32);
    u16* R1a = (u16*)(ws + 2 * MB32);
    u16* R1b = (u16*)(ws + 3 * MB32);
    float* sigma = (float*)(ws + 4 * MB32);
    u16* Eh = (u16*)(ws + 4 * MB32);
    u16* El = (u16*)(ws + 5 * MB32);
    u16* Sh = (u16*)(ws + 6 * MB32);
    u16* Sl = (u16*)(ws + 7 * MB32);
    u16* R2a = (u16*)(ws + 8 * MB32);
    u16* R2b = (u16*)(ws + 9 * MB32);
    float* rtr = (float*)(ws + 10 * MB32);

    center_kernel<<<Nn, 256, 0, stream>>>(x, xn, xnT);
    sigma_kernel<<<Nn * 4, 256, 0, stream>>>(xnT, sigma);
    normalize_kernel<<<Nn, 256, 0, stream>>>(sigma, Sh, Sl, R2a, R2b, rtr);  // P1 in R2

    // it1: P in R2
    ns_gemm<<<Nn * 4, 256, 0, stream>>>(R2a, R2b, R2a, R2b, R1a, R1b, rtr, 0);  // Q -> R1
    ns_gemm<<<Nn * 4, 256, 0, stream>>>(R1a, R1b, Sh, Sl, Eh, El, rtr, 1);      // E
    ns_gemm<<<Nn * 4, 256, 0, stream>>>(R2a, R2b, Eh, El, R1a, R1b, rtr, 0);    // P2 -> R1
    // it2: P in R1
    ns_gemm<<<Nn * 4, 256, 0, stream>>>(R1a, R1b, R1a, R1b, R2a, R2b, rtr, 0);  // Q -> R2
    ns_gemm<<<Nn * 4, 256, 0, stream>>>(R2a, R2b, Sh, Sl, Eh, El, rtr, 1);      // E
    ns_gemm<<<Nn * 4, 256, 0, stream>>>(R1a, R1b, Eh, El, R2a, R2b, rtr, 0);    // P3 -> R2
    // it3: P in R2
    ns_gemm<<<Nn * 4, 256, 0, stream>>>(R2a, R2b, R2a, R2b, R1a, R1b, rtr, 0);  // Q -> R1
    ns_gemm<<<Nn * 4, 256, 0, stream>>>(R1a, R1b, Sh, Sl, Eh, El, rtr, 1);      // E
    ns_gemm<<<Nn * 4, 256, 0, stream>>>(R2a, R2b, Eh, El, R1a, R1b, rtr, 2);    // W bf16 -> R1a

    final_gemm<<<Nn * 8, 256, 0, stream>>>(xn, R1a, out);
}

// Round 3
// 634.324 us; speedup vs baseline: 1.8335x; 1.2968x over previous
//
#include <hip/hip_runtime.h>
#include <stdint.h>

#define Nn 256
#define Mm 512
#define Dd 256

typedef unsigned short u16;
typedef unsigned int u32;
typedef __attribute__((ext_vector_type(8))) short bf16x8;
typedef __attribute__((ext_vector_type(4))) float f32x4;

__device__ __forceinline__ u16 f2b(float f) {
    unsigned u = __float_as_uint(f);
    return (u16)((u + 0x7FFFu + ((u >> 16) & 1u)) >> 16);  // RNE to bf16
}
__device__ __forceinline__ float b2f(u16 h) {
    return __uint_as_float(((unsigned)h) << 16);
}
__device__ __forceinline__ void glds16(const u16* g, u16* l) {
    __builtin_amdgcn_global_load_lds((const __attribute__((address_space(1))) void*)g,
                                     (__attribute__((address_space(3))) void*)l, 16, 0, 0);
}

// ---------------------------------------------------------------------------
// Kernel 1a: partial column sums. grid = Nn*4; block (n, c) sums 128 rows.
// meanPart[n][c][d], no atomics, no pre-zero needed.
// ---------------------------------------------------------------------------
__global__ __launch_bounds__(256) void mean_part_kernel(const float* __restrict__ x,
                                                        float* __restrict__ meanPart) {
    const int bid = blockIdx.x;
    const int n = bid >> 2, c = bid & 3;
    const int tid = threadIdx.x;
    const float* xb = x + (size_t)n * Mm * Dd + (size_t)c * 128 * Dd;
    float a0 = 0.f, a1 = 0.f, a2 = 0.f, a3 = 0.f;
    for (int m = 0; m < 128; m += 4) {
        a0 += xb[(m + 0) * Dd + tid];
        a1 += xb[(m + 1) * Dd + tid];
        a2 += xb[(m + 2) * Dd + tid];
        a3 += xb[(m + 3) * Dd + tid];
    }
    meanPart[((size_t)n * 4 + c) * Dd + tid] = a0 + a1 + a2 + a3;
}

// ---------------------------------------------------------------------------
// Kernel 1b: center + emit xn bf16 [n][m][d] and xnT bf16 [n][d][m].
// grid = Nn*8; block (n, mt) handles 64 m-rows x 256 d. 8 blocks/CU.
// ---------------------------------------------------------------------------
__global__ __launch_bounds__(256) void center_tr_kernel(const float* __restrict__ x,
                                                        const float* __restrict__ meanPart,
                                                        u16* __restrict__ xn,
                                                        u16* __restrict__ xnT) {
    __shared__ float meanS[Dd];
    __shared__ u16 tileS[64 * 66];
    const int bid = blockIdx.x;
    const int n = bid >> 3, mt = bid & 7;
    const int tid = threadIdx.x;

    const float* mp = meanPart + (size_t)n * 4 * Dd;
    meanS[tid] = (mp[tid] + mp[Dd + tid] + mp[2 * Dd + tid] + mp[3 * Dd + tid]) * (1.0f / Mm);
    __syncthreads();

    const float* xb = x + (size_t)n * Mm * Dd;
    u16* xnb = xn + (size_t)n * Mm * Dd;
    u16* xtb = xnT + (size_t)n * Dd * Mm;
    const int mrow = tid >> 4, dq = tid & 15;      // phase A
    const int tx2 = (tid & 31) * 2, ty = tid >> 5; // phase B

    for (int dt = 0; dt < Dd / 64; ++dt) {
        #pragma unroll
        for (int rr = 0; rr < 4; ++rr) {
            int ml = mrow + 16 * rr;
            int m = mt * 64 + ml;
            int d = dt * 64 + dq * 4;
            float4 v = *(const float4*)(xb + (size_t)m * Dd + d);
            float4 mu = *(const float4*)(meanS + d);
            u16 b0 = f2b(v.x - mu.x), b1 = f2b(v.y - mu.y);
            u16 b2 = f2b(v.z - mu.z), b3 = f2b(v.w - mu.w);
            u32 lo = (u32)b0 | ((u32)b1 << 16);
            u32 hi = (u32)b2 | ((u32)b3 << 16);
            *(uint2*)(xnb + (size_t)m * Dd + d) = make_uint2(lo, hi);
            tileS[(dq * 4 + 0) * 66 + ml] = b0;
            tileS[(dq * 4 + 1) * 66 + ml] = b1;
            tileS[(dq * 4 + 2) * 66 + ml] = b2;
            tileS[(dq * 4 + 3) * 66 + ml] = b3;
        }
        __syncthreads();
        #pragma unroll
        for (int r = 0; r < 8; ++r) {
            int dl = r * 8 + ty;
            u32 w = *(const u32*)(tileS + dl * 66 + tx2);
            *(u32*)(xtb + (size_t)(dt * 64 + dl) * Mm + mt * 64 + tx2) = w;
        }
        __syncthreads();
    }
}

// ---------------------------------------------------------------------------
// Kernel 2: sigma[n] = XnT @ XnT^T (raw fp32). XCD-swizzled.
// ---------------------------------------------------------------------------
__global__ __launch_bounds__(256) void sigma_kernel(const u16* __restrict__ xnT,
                                                    float* __restrict__ sigma) {
    __shared__ u16 sA[128 * 32];
    __shared__ u16 sB[128 * 32];
    const int bid = blockIdx.x;
    const int xcd = bid & 7, slot = bid >> 3;
    const int t = slot & 3;
    const int n = ((slot >> 2) << 3) | xcd;
    const int tr = t >> 1, tc = t & 1;
    const int tid = threadIdx.x;
    const int lane = tid & 63, wave = tid >> 6;
    const int wr = wave >> 1, wc = wave & 1;
    const int l15 = lane & 15, quad = lane >> 4;
    const int row0 = tid >> 2, q = tid & 3;
    const int wb8 = (tid & 192) * 8;

    const u16* base = xnT + (size_t)n * Dd * Mm;
    const u16* gA = base + (size_t)(tr * 128) * Mm;
    const u16* gB = base + (size_t)(tc * 128) * Mm;

    f32x4 acc[4][4];
    #pragma unroll
    for (int i = 0; i < 4; ++i)
        #pragma unroll
        for (int j = 0; j < 4; ++j) acc[i][j] = (f32x4){0.f, 0.f, 0.f, 0.f};

    for (int kk = 0; kk < Mm; kk += 32) {
        glds16(gA + (size_t)row0 * Mm + kk + q * 8, sA + wb8);
        glds16(gA + (size_t)(row0 + 64) * Mm + kk + q * 8, sA + 2048 + wb8);
        glds16(gB + (size_t)row0 * Mm + kk + q * 8, sB + wb8);
        glds16(gB + (size_t)(row0 + 64) * Mm + kk + q * 8, sB + 2048 + wb8);
        __syncthreads();
        bf16x8 a[4], b[4];
        #pragma unroll
        for (int i = 0; i < 4; ++i) a[i] = *(const bf16x8*)(sA + (wr * 64 + i * 16 + l15) * 32 + quad * 8);
        #pragma unroll
        for (int j = 0; j < 4; ++j) b[j] = *(const bf16x8*)(sB + (wc * 64 + j * 16 + l15) * 32 + quad * 8);
        #pragma unroll
        for (int i = 0; i < 4; ++i)
            #pragma unroll
            for (int j = 0; j < 4; ++j)
                acc[i][j] = __builtin_amdgcn_mfma_f32_16x16x32_bf16(a[i], b[j], acc[i][j], 0, 0, 0);
        __syncthreads();
    }

    float* sg = sigma + (size_t)n * Dd * Dd;
    #pragma unroll
    for (int i = 0; i < 4; ++i)
        #pragma unroll
        for (int j = 0; j < 4; ++j)
            #pragma unroll
            for (int r = 0; r < 4; ++r) {
                int row = tr * 128 + wr * 64 + i * 16 + quad * 4 + r;
                int col = tc * 128 + wc * 64 + j * 16 + l15;
                sg[row * Dd + col] = acc[i][j][r];
            }
}

// ---------------------------------------------------------------------------
// Kernel 3: trace reduce; S = sigma/tr split (Sh,Sl); P1 = 1.5I - 0.5S plain
// bf16; rtr = sqrt(511/tr).
// ---------------------------------------------------------------------------
__global__ __launch_bounds__(256) void normalize_kernel(const float* __restrict__ sigma,
                                                        u16* __restrict__ Sh, u16* __restrict__ Sl,
                                                        u16* __restrict__ P,
                                                        float* __restrict__ rtr) {
    __shared__ float red[256];
    const int n = blockIdx.x, tid = threadIdx.x;
    const float* sg = sigma + (size_t)n * Dd * Dd;
    red[tid] = sg[tid * (Dd + 1)];
    __syncthreads();
    for (int s = 128; s > 0; s >>= 1) {
        if (tid < s) red[tid] += red[tid + s];
        __syncthreads();
    }
    const float raw = red[0];
    const float inv = 1.0f / raw;
    if (tid == 0) rtr[n] = sqrtf(511.0f * inv);

    const size_t mb = (size_t)n * Dd * Dd;
    for (int r = 0; r < Dd; ++r) {
        size_t idx = mb + (size_t)r * Dd + tid;
        float s = sg[r * Dd + tid] * inv;
        u16 sh = f2b(s);
        Sh[idx] = sh;
        Sl[idx] = f2b(s - b2f(sh));
        P[idx] = f2b(((r == tid) ? 1.5f : 0.0f) - 0.5f * s);
    }
}

// ---------------------------------------------------------------------------
// Kernel 4: batched GEMM on symmetric 256x256 bf16 operands (B reads rows).
// acc = A@Bh (+ A@Bl if bsplit).
//  mode 0: out = bf16(acc)
//  mode 1: out = bf16(1.5I - 0.5*acc)     (E-step; B = S split)
//  mode 2: out = bf16(acc * rtr[n])       (W)
// XCD-swizzled: batch's 4 blocks on one XCD.
// ---------------------------------------------------------------------------
__global__ __launch_bounds__(256) void ns_gemm(const u16* __restrict__ A,
                                               const u16* __restrict__ Bh, const u16* __restrict__ Bl,
                                               u16* __restrict__ outH,
                                               const float* __restrict__ rtr, int mode, int bsplit) {
    __shared__ u16 sA[128 * 32], sBh[128 * 32], sBl[128 * 32];
    const int bid = blockIdx.x;
    const int xcd = bid & 7, slot = bid >> 3;
    const int t = slot & 3;
    const int n = ((slot >> 2) << 3) | xcd;
    const int tr = t >> 1, tc = t & 1;
    const int tid = threadIdx.x;
    const int lane = tid & 63, wave = tid >> 6;
    const int wr = wave >> 1, wc = wave & 1;
    const int l15 = lane & 15, quad = lane >> 4;
    const int row0 = tid >> 2, q = tid & 3;
    const int wb8 = (tid & 192) * 8;

    const size_t mb = (size_t)n * Dd * Dd;
    const u16* gA = A + mb + (size_t)(tr * 128) * Dd;
    const u16* gBh = Bh + mb + (size_t)(tc * 128) * Dd;
    const u16* gBl = Bl + mb + (size_t)(tc * 128) * Dd;

    f32x4 acc[4][4];
    #pragma unroll
    for (int i = 0; i < 4; ++i)
        #pragma unroll
        for (int j = 0; j < 4; ++j) acc[i][j] = (f32x4){0.f, 0.f, 0.f, 0.f};

    for (int kk = 0; kk < Dd; kk += 32) {
        glds16(gA + (size_t)row0 * Dd + kk + q * 8, sA + wb8);
        glds16(gA + (size_t)(row0 + 64) * Dd + kk + q * 8, sA + 2048 + wb8);
        glds16(gBh + (size_t)row0 * Dd + kk + q * 8, sBh + wb8);
        glds16(gBh + (size_t)(row0 + 64) * Dd + kk + q * 8, sBh + 2048 + wb8);
        if (bsplit) {
            glds16(gBl + (size_t)row0 * Dd + kk + q * 8, sBl + wb8);
            glds16(gBl + (size_t)(row0 + 64) * Dd + kk + q * 8, sBl + 2048 + wb8);
        }
        __syncthreads();
        bf16x8 a[4], bh[4];
        #pragma unroll
        for (int i = 0; i < 4; ++i) a[i] = *(const bf16x8*)(sA + (wr * 64 + i * 16 + l15) * 32 + quad * 8);
        #pragma unroll
        for (int j = 0; j < 4; ++j) bh[j] = *(const bf16x8*)(sBh + (wc * 64 + j * 16 + l15) * 32 + quad * 8);
        #pragma unroll
        for (int i = 0; i < 4; ++i)
            #pragma unroll
            for (int j = 0; j < 4; ++j)
                acc[i][j] = __builtin_amdgcn_mfma_f32_16x16x32_bf16(a[i], bh[j], acc[i][j], 0, 0, 0);
        if (bsplit) {
            bf16x8 bl[4];
            #pragma unroll
            for (int j = 0; j < 4; ++j) bl[j] = *(const bf16x8*)(sBl + (wc * 64 + j * 16 + l15) * 32 + quad * 8);
            #pragma unroll
            for (int i = 0; i < 4; ++i)
                #pragma unroll
                for (int j = 0; j < 4; ++j)
                    acc[i][j] = __builtin_amdgcn_mfma_f32_16x16x32_bf16(a[i], bl[j], acc[i][j], 0, 0, 0);
        }
        __syncthreads();
    }

    const float rs = (mode == 2) ? rtr[n] : 0.f;
    #pragma unroll
    for (int i = 0; i < 4; ++i)
        #pragma unroll
        for (int j = 0; j < 4; ++j)
            #pragma unroll
            for (int r = 0; r < 4; ++r) {
                int row = tr * 128 + wr * 64 + i * 16 + quad * 4 + r;
                int col = tc * 128 + wc * 64 + j * 16 + l15;
                size_t idx = mb + (size_t)row * Dd + col;
                float v = acc[i][j][r];
                float o;
                if (mode == 0) o = v;
                else if (mode == 1) o = ((row == col) ? 1.5f : 0.0f) - 0.5f * v;
                else o = v * rs;
                outH[idx] = f2b(o);
            }
}

// ---------------------------------------------------------------------------
// Kernel 5: out = Xn @ W (W symmetric bf16). fp32 out. XCD-swizzled.
// ---------------------------------------------------------------------------
__global__ __launch_bounds__(256) void final_gemm(const u16* __restrict__ xn,
                                                  const u16* __restrict__ Wh,
                                                  float* __restrict__ out) {
    __shared__ u16 sA[128 * 32];
    __shared__ u16 sB[128 * 32];
    const int bid = blockIdx.x;
    const int xcd = bid & 7, slot = bid >> 3;
    const int t = slot & 7;
    const int n = ((slot >> 3) << 3) | xcd;
    const int tr = t >> 1, tc = t & 1;
    const int tid = threadIdx.x;
    const int lane = tid & 63, wave = tid >> 6;
    const int wr = wave >> 1, wc = wave & 1;
    const int l15 = lane & 15, quad = lane >> 4;
    const int row0 = tid >> 2, q = tid & 3;
    const int wb8 = (tid & 192) * 8;

    const u16* gA = xn + (size_t)n * Mm * Dd + (size_t)(tr * 128) * Dd;
    const u16* gB = Wh + (size_t)n * Dd * Dd + (size_t)(tc * 128) * Dd;

    f32x4 acc[4][4];
    #pragma unroll
    for (int i = 0; i < 4; ++i)
        #pragma unroll
        for (int j = 0; j < 4; ++j) acc[i][j] = (f32x4){0.f, 0.f, 0.f, 0.f};

    for (int kk = 0; kk < Dd; kk += 32) {
        glds16(gA + (size_t)row0 * Dd + kk + q * 8, sA + wb8);
        glds16(gA + (size_t)(row0 + 64) * Dd + kk + q * 8, sA + 2048 + wb8);
        glds16(gB + (size_t)row0 * Dd + kk + q * 8, sB + wb8);
        glds16(gB + (size_t)(row0 + 64) * Dd + kk + q * 8, sB + 2048 + wb8);
        __syncthreads();
        bf16x8 a[4], b[4];
        #pragma unroll
        for (int i = 0; i < 4; ++i) a[i] = *(const bf16x8*)(sA + (wr * 64 + i * 16 + l15) * 32 + quad * 8);
        #pragma unroll
        for (int j = 0; j < 4; ++j) b[j] = *(const bf16x8*)(sB + (wc * 64 + j * 16 + l15) * 32 + quad * 8);
        #pragma unroll
        for (int i = 0; i < 4; ++i)
            #pragma unroll
            for (int j = 0; j < 4; ++j)
                acc[i][j] = __builtin_amdgcn_mfma_f32_16x16x32_bf16(a[i], b[j], acc[i][j], 0, 0, 0);
        __syncthreads();
    }

    float* ob = out + (size_t)n * Mm * Dd;
    #pragma unroll
    for (int i = 0; i < 4; ++i)
        #pragma unroll
        for (int j = 0; j < 4; ++j)
            #pragma unroll
            for (int r = 0; r < 4; ++r) {
                int row = tr * 128 + wr * 64 + i * 16 + quad * 4 + r;
                int col = tc * 128 + wc * 64 + j * 16 + l15;
                ob[(size_t)row * Dd + col] = acc[i][j][r];
            }
}

// ---------------------------------------------------------------------------
// Workspace (32MB units):
//  u0-1 xn | u2-3 xnT (dead after sigma) -> u2=P-ping, u3=E
//  u4-5 sigma fp32 (dead after normalize) -> u4=Q, u5=P-pong/W
//  u6 Sh | u7 Sl | u9 meanPart(1MB) + rtr
// NS per iter: Q=P@P (m0); E=1.5I-0.5(Q@S) (m1,split-B); P'=P@E (m0/m2).
// ---------------------------------------------------------------------------
extern "C" void kernel_launch(void* const* d_in, const int* in_sizes, int n_in,
                              void* d_out, int out_size, void* d_ws, size_t ws_size,
                              hipStream_t stream) {
    const float* x = (const float*)d_in[0];
    float* out = (float*)d_out;
    char* ws = (char*)d_ws;
    const size_t MB32 = 33554432;

    u16* xn = (u16*)(ws + 0);
    u16* xnT = (u16*)(ws + 2 * MB32);
    u16* P0 = (u16*)(ws + 2 * MB32);   // alias xnT (dead after sigma)
    u16* E = (u16*)(ws + 3 * MB32);
    float* sigma = (float*)(ws + 4 * MB32);
    u16* Q = (u16*)(ws + 4 * MB32);    // alias sigma (dead after normalize)
    u16* P1 = (u16*)(ws + 5 * MB32);
    u16* Sh = (u16*)(ws + 6 * MB32);
    u16* Sl = (u16*)(ws + 7 * MB32);
    float* meanPart = (float*)(ws + 9 * MB32);
    float* rtr = (float*)(ws + 9 * MB32 + 4194304);

    mean_part_kernel<<<Nn * 4, 256, 0, stream>>>(x, meanPart);
    center_tr_kernel<<<Nn * 8, 256, 0, stream>>>(x, meanPart, xn, xnT);
    sigma_kernel<<<Nn * 4, 256, 0, stream>>>(xnT, sigma);
    normalize_kernel<<<Nn, 256, 0, stream>>>(sigma, Sh, Sl, P0, rtr);  // P1 -> u2

    // it1: P = u2
    ns_gemm<<<Nn * 4, 256, 0, stream>>>(P0, P0, P0, Q, rtr, 0, 0);   // Q = P@P
    ns_gemm<<<Nn * 4, 256, 0, stream>>>(Q, Sh, Sl, E, rtr, 1, 1);    // E = 1.5I-0.5 Q@S
    ns_gemm<<<Nn * 4, 256, 0, stream>>>(P0, E, E, P1, rtr, 0, 0);    // P2 -> u5
    // it2: P = u5
    ns_gemm<<<Nn * 4, 256, 0, stream>>>(P1, P1, P1, Q, rtr, 0, 0);
    ns_gemm<<<Nn * 4, 256, 0, stream>>>(Q, Sh, Sl, E, rtr, 1, 1);
    ns_gemm<<<Nn * 4, 256, 0, stream>>>(P1, E, E, P0, rtr, 0, 0);    // P3 -> u2
    // it3: P = u2
    ns_gemm<<<Nn * 4, 256, 0, stream>>>(P0, P0, P0, Q, rtr, 0, 0);
    ns_gemm<<<Nn * 4, 256, 0, stream>>>(Q, Sh, Sl, E, rtr, 1, 1);
    ns_gemm<<<Nn * 4, 256, 0, stream>>>(P0, E, E, P1, rtr, 2, 0);    // W -> u5

    final_gemm<<<Nn * 8, 256, 0, stream>>>(xn, P1, out);
}